// Round 2
// baseline (849.004 us; speedup 1.0000x reference)
//
#include <hip/hip_runtime.h>
#include <hip/hip_bf16.h>

#define BB 2
#define NN 2048
#define DD 128
#define BN (BB*NN)
#define CAP 128
#define INV_SQRT_D 0.08838834764831845f

// ---------------------------------------------------------------------------
// Build padded CSR of the transposed masked edge matrix.
// e_t[b, dst, src] = edge[b, src, dst] * A[b, src, dst].
// Iterate A/edge row-major (coalesced); append src j into dst row via atomics.
// cols[] stores GLOBAL src row (b*NN + src) so k/v gathers index directly.
// ---------------------------------------------------------------------------
__global__ __launch_bounds__(256) void build_csr(
    const float* __restrict__ A,
    const float* __restrict__ edge,
    int* __restrict__ deg, int* __restrict__ cols, float* __restrict__ evals)
{
    int idx = blockIdx.x * blockDim.x + threadIdx.x;   // over B*N*N
    float a = A[idx];
    if (a != 0.f) {
        int c = idx % NN;            // dst i
        int r = (idx / NN) % NN;     // src j
        int b = idx / (NN * NN);
        int row = b * NN + c;
        int slot = atomicAdd(&deg[row], 1);
        if (slot < CAP) {
            cols[row * CAP + slot]  = b * NN + r;      // global src row
            evals[row * CAP + slot] = edge[idx] * a;
        }
    }
}

__global__ __launch_bounds__(256) void cast_node(
    const float* __restrict__ node, float* __restrict__ x0)
{
    int i = blockIdx.x * blockDim.x + threadIdx.x;   // BN
    x0[i] = node[i];
}

// ---------------------------------------------------------------------------
// Fused projection: out cols = [ q(H*D) | k(H*D) | v(H*D) | skip(D) ]
// x: (BN, FIN) fp32.  Wq/Wk/Wv: (FIN, H*D).  Ws: (FIN, D).
// grid: (BN/8, ncols/128), block 128.  Each block: 8 rows x 128 cols.
// ---------------------------------------------------------------------------
template<int FIN>
__global__ __launch_bounds__(128) void proj_kernel(
    const float* __restrict__ x,
    const float* __restrict__ Wq,
    const float* __restrict__ Wk,
    const float* __restrict__ Wv,
    const float* __restrict__ Ws,
    float* __restrict__ q, float* __restrict__ k,
    float* __restrict__ v, float* __restrict__ skip,
    int H)
{
    const int HD = H * DD;
    __shared__ float xs[8][FIN];
    int row0 = blockIdx.x * 8;
    int col  = blockIdx.y * 128 + threadIdx.x;

    for (int idx = threadIdx.x; idx < 8 * FIN; idx += 128) {
        int r = idx / FIN, f = idx % FIN;
        xs[r][f] = x[(row0 + r) * FIN + f];
    }
    __syncthreads();

    const float* W; float* out; int lcol; int ldw; int odim;
    if      (col < HD)     { W = Wq; out = q;    lcol = col;          ldw = HD; odim = HD; }
    else if (col < 2*HD)   { W = Wk; out = k;    lcol = col - HD;     ldw = HD; odim = HD; }
    else if (col < 3*HD)   { W = Wv; out = v;    lcol = col - 2*HD;   ldw = HD; odim = HD; }
    else                   { W = Ws; out = skip; lcol = col - 3*HD;   ldw = DD; odim = DD; }

    float acc[8];
#pragma unroll
    for (int r = 0; r < 8; r++) acc[r] = 0.f;
    for (int f = 0; f < FIN; f++) {
        float wf = W[f * ldw + lcol];
#pragma unroll
        for (int r = 0; r < 8; r++) acc[r] += xs[r][f] * wf;
    }
#pragma unroll
    for (int r = 0; r < 8; r++) out[(row0 + r) * odim + lcol] = acc[r];
}

// ---------------------------------------------------------------------------
// Sparse transformer-conv attention. One block (256 thr = 4 waves) per dst.
// ---------------------------------------------------------------------------
__global__ __launch_bounds__(256) void attn_kernel(
    const float* __restrict__ q, const float* __restrict__ k,
    const float* __restrict__ v, const float* __restrict__ skip,
    const int* __restrict__ deg, const int* __restrict__ cols,
    const float* __restrict__ evals,
    const float* __restrict__ We,
    float* __restrict__ out, int H, int meanheads)
{
    const int HD = H * DD;
    int row  = blockIdx.x;
    int tid  = threadIdx.x;
    int lane = tid & 63, wid = tid >> 6;

    __shared__ float qs[256];     // q_i (H*D <= 256)
    __shared__ float sc[256];     // per (h, m) scores -> unnormalized alpha
    __shared__ int   jc[CAP];
    __shared__ float ev[CAP];
    __shared__ float qe[2];
    __shared__ float invZ[2];
    __shared__ float ewred[2];
    __shared__ float hout[256];

    int dg = min(deg[row], CAP);

    for (int i = tid; i < HD; i += 256) qs[i] = q[(size_t)row * HD + i];
    for (int m = tid; m < dg; m += 256) {
        jc[m] = cols[row * CAP + m];
        ev[m] = evals[row * CAP + m];
    }
    __syncthreads();

    // qe[h] = q_i[h] . We[h]  (wave h computes)
    if (wid < H) {
        float p = qs[wid * DD + lane * 2]     * We[wid * DD + lane * 2]
                + qs[wid * DD + lane * 2 + 1] * We[wid * DD + lane * 2 + 1];
        for (int off = 32; off; off >>= 1) p += __shfl_down(p, off);
        if (lane == 0) qe[wid] = p;
    }
    __syncthreads();

    // scores: one edge per wave round-robin
    for (int m = wid; m < dg; m += 4) {
        int j = jc[m];
        float e = ev[m];
        for (int h = 0; h < H; h++) {
            const float* kr = &k[(size_t)j * HD + h * DD];
            float p = qs[h * DD + lane * 2]     * kr[lane * 2]
                    + qs[h * DD + lane * 2 + 1] * kr[lane * 2 + 1];
            for (int off = 32; off; off >>= 1) p += __shfl_down(p, off);
            if (lane == 0) sc[h * CAP + m] = (p + qe[h] * e) * INV_SQRT_D;
        }
    }
    __syncthreads();

    // masked softmax per head (wave h handles head h; dg <= 128 -> 2 elems/lane)
    if (wid < H) {
        float s0 = (lane < dg)      ? sc[wid * CAP + lane]      : -INFINITY;
        float s1 = (lane + 64 < dg) ? sc[wid * CAP + lane + 64] : -INFINITY;
        float mx = fmaxf(s0, s1);
        for (int off = 32; off; off >>= 1) mx = fmaxf(mx, __shfl_down(mx, off));
        mx = __shfl(mx, 0);
        float e0 = (lane < dg)      ? __expf(s0 - mx) : 0.f;
        float e1 = (lane + 64 < dg) ? __expf(s1 - mx) : 0.f;
        if (lane < dg)      sc[wid * CAP + lane]      = e0;
        if (lane + 64 < dg) sc[wid * CAP + lane + 64] = e1;
        float z  = e0 + e1;
        float ew = e0 * ((lane < dg) ? ev[lane] : 0.f)
                 + e1 * ((lane + 64 < dg) ? ev[lane + 64] : 0.f);
        for (int off = 32; off; off >>= 1) { z += __shfl_down(z, off); ew += __shfl_down(ew, off); }
        if (lane == 0) { invZ[wid] = (z > 0.f) ? 1.f / z : 0.f; ewred[wid] = ew; }
    }
    __syncthreads();

    // aggregation: thread t -> (head h, channel c)
    if (tid < HD) {
        int h = tid / DD, c = tid % DD;
        float acc = 0.f;
        for (int m = 0; m < dg; m++) {
            acc += sc[h * CAP + m] * v[(size_t)jc[m] * HD + h * DD + c];
        }
        float r = (acc + ewred[h] * We[h * DD + c]) * invZ[h];
        hout[tid] = r;
    }
    __syncthreads();

    if (tid < DD) {
        float r = hout[tid];
        if (meanheads) r = 0.5f * (r + hout[DD + tid]);
        out[(size_t)row * DD + tid] = r + skip[(size_t)row * DD + tid];
    }
}

// ---------------------------------------------------------------------------
// LayerNorm (eps=1e-5) + ReLU in-place over feature dim 128.
// ---------------------------------------------------------------------------
__global__ __launch_bounds__(128) void ln_relu(float* __restrict__ x)
{
    int row = blockIdx.x, t = threadIdx.x;
    float vx = x[(size_t)row * DD + t];
    __shared__ float s[4];
    float sum = vx, sq = vx * vx;
    int lane = t & 63, wid = t >> 6;
    for (int off = 32; off; off >>= 1) { sum += __shfl_down(sum, off); sq += __shfl_down(sq, off); }
    if (lane == 0) { s[wid] = sum; s[2 + wid] = sq; }
    __syncthreads();
    float mu  = (s[0] + s[1]) * (1.f / DD);
    float var = (s[2] + s[3]) * (1.f / DD) - mu * mu;
    float y = (vx - mu) * rsqrtf(var + 1e-5f);
    x[(size_t)row * DD + t] = fmaxf(y, 0.f);
}

// ---------------------------------------------------------------------------
extern "C" void kernel_launch(void* const* d_in, const int* in_sizes, int n_in,
                              void* d_out, int out_size, void* d_ws, size_t ws_size,
                              hipStream_t stream)
{
    const float* node = (const float*)d_in[0];
    const float* edge = (const float*)d_in[1];
    const float* A    = (const float*)d_in[2];
    const float* Wq[3] = {(const float*)d_in[3],  (const float*)d_in[8],  (const float*)d_in[13]};
    const float* Wk[3] = {(const float*)d_in[4],  (const float*)d_in[9],  (const float*)d_in[14]};
    const float* Wv[3] = {(const float*)d_in[5],  (const float*)d_in[10], (const float*)d_in[15]};
    const float* We[3] = {(const float*)d_in[6],  (const float*)d_in[11], (const float*)d_in[16]};
    const float* Ws[3] = {(const float*)d_in[7],  (const float*)d_in[12], (const float*)d_in[17]};

    // workspace carve
    char* p = (char*)d_ws;
    float* emb_a = (float*)p; p += (size_t)BN * DD * 4;
    float* emb_b = (float*)p; p += (size_t)BN * DD * 4;
    float* qbuf  = (float*)p; p += (size_t)BN * 256 * 4;
    float* kbuf  = (float*)p; p += (size_t)BN * 256 * 4;
    float* vbuf  = (float*)p; p += (size_t)BN * 256 * 4;
    float* sbuf  = (float*)p; p += (size_t)BN * DD * 4;
    int*   degb  = (int*)p;   p += (size_t)BN * 4;
    int*   colb  = (int*)p;   p += (size_t)BN * CAP * 4;
    float* evb   = (float*)p; p += (size_t)BN * CAP * 4;

    hipMemsetAsync(degb, 0, (size_t)BN * 4, stream);
    build_csr<<<(BB * NN * NN) / 256, 256, 0, stream>>>(A, edge, degb, colb, evb);
    cast_node<<<BN / 256, 256, 0, stream>>>(node, emb_a);

    float* x = emb_a;
    float* y = emb_b;

    // (layer index, apply LN+ReLU after)
    const int  appL [7] = {0, 1, 2, 1, 2, 1, 2};
    const bool appLN[7] = {true, true, false, true, false, true, false};

    for (int a = 0; a < 7; a++) {
        int l = appL[a];
        int H = (l == 2) ? 2 : 1;
        int ncols = 3 * H * DD + DD;
        dim3 pgrid(BN / 8, ncols / 128);
        if (l == 0)
            proj_kernel<1><<<pgrid, 128, 0, stream>>>(x, Wq[l], Wk[l], Wv[l], Ws[l],
                                                      qbuf, kbuf, vbuf, sbuf, H);
        else
            proj_kernel<DD><<<pgrid, 128, 0, stream>>>(x, Wq[l], Wk[l], Wv[l], Ws[l],
                                                       qbuf, kbuf, vbuf, sbuf, H);
        float* dst = (a == 6) ? (float*)d_out : y;
        attn_kernel<<<BN, 256, 0, stream>>>(qbuf, kbuf, vbuf, sbuf, degb, colb, evb,
                                            We[l], dst, H, (l == 2) ? 1 : 0);
        if (appLN[a]) ln_relu<<<BN, 128, 0, stream>>>(dst);
        float* t = x; x = dst; y = t;
    }
}

// Round 3
// 577.118 us; speedup vs baseline: 1.4711x; 1.4711x over previous
//
#include <hip/hip_runtime.h>
#include <hip/hip_bf16.h>

#define BB 2
#define NN 2048
#define DD 128
#define BN (BB*NN)
#define CAP 128
#define INV_SQRT_D 0.08838834764831845f

// ---------------------------------------------------------------------------
// Build padded CSR of e_t[b,dst,src] = edge[b,src,dst]*A[b,src,dst].
// cols[] stores GLOBAL src row (b*NN + src).
// ---------------------------------------------------------------------------
__global__ __launch_bounds__(256) void build_csr(
    const float* __restrict__ A,
    const float* __restrict__ edge,
    int* __restrict__ deg, int* __restrict__ cols, float* __restrict__ evals)
{
    int idx = blockIdx.x * blockDim.x + threadIdx.x;   // over B*N*N
    float a = A[idx];
    if (a != 0.f) {
        int c = idx % NN;            // dst i
        int r = (idx / NN) % NN;     // src j
        int b = idx / (NN * NN);
        int row = b * NN + c;
        int slot = atomicAdd(&deg[row], 1);
        if (slot < CAP) {
            cols[row * CAP + slot]  = b * NN + r;      // global src row
            evals[row * CAP + slot] = edge[idx] * a;
        }
    }
}

__global__ __launch_bounds__(256) void cast_node(
    const float* __restrict__ node, float* __restrict__ x0)
{
    int i = blockIdx.x * blockDim.x + threadIdx.x;   // BN
    x0[i] = node[i];
}

// ---------------------------------------------------------------------------
// Fused projection: out cols = [ q(H*D) | k(H*D) | v(H*D) | skip(D) ]
// grid: (BN/16, ncols/128), block 128.  Each block: 16 rows x 128 cols.
// ---------------------------------------------------------------------------
template<int FIN>
__global__ __launch_bounds__(128) void proj_kernel(
    const float* __restrict__ x,
    const float* __restrict__ Wq,
    const float* __restrict__ Wk,
    const float* __restrict__ Wv,
    const float* __restrict__ Ws,
    float* __restrict__ q, float* __restrict__ k,
    float* __restrict__ v, float* __restrict__ skip,
    int H)
{
    const int HD = H * DD;
    __shared__ float xs[16][FIN];
    int row0 = blockIdx.x * 16;
    int col  = blockIdx.y * 128 + threadIdx.x;

    if constexpr (FIN % 4 == 0) {
        const float4* xp  = (const float4*)&x[(size_t)row0 * FIN];
        float4*       xsp = (float4*)&xs[0][0];
        for (int i = threadIdx.x; i < 16 * FIN / 4; i += 128) xsp[i] = xp[i];
    } else {
        for (int idx = threadIdx.x; idx < 16 * FIN; idx += 128)
            xs[idx / FIN][idx % FIN] = x[(size_t)(row0 + idx / FIN) * FIN + idx % FIN];
    }
    __syncthreads();

    const float* W; float* out; int lcol; int ldw; int odim;
    if      (col < HD)     { W = Wq; out = q;    lcol = col;          ldw = HD; odim = HD; }
    else if (col < 2*HD)   { W = Wk; out = k;    lcol = col - HD;     ldw = HD; odim = HD; }
    else if (col < 3*HD)   { W = Wv; out = v;    lcol = col - 2*HD;   ldw = HD; odim = HD; }
    else                   { W = Ws; out = skip; lcol = col - 3*HD;   ldw = DD; odim = DD; }

    float acc[16];
#pragma unroll
    for (int r = 0; r < 16; r++) acc[r] = 0.f;
    for (int f = 0; f < FIN; f++) {
        float wf = W[(size_t)f * ldw + lcol];
#pragma unroll
        for (int r = 0; r < 16; r++) acc[r] += xs[r][f] * wf;
    }
#pragma unroll
    for (int r = 0; r < 16; r++) out[(size_t)(row0 + r) * odim + lcol] = acc[r];
}

// ---------------------------------------------------------------------------
// Wave-synchronous sparse transformer-conv attention.
// One wave per dst row, 4 rows per block, no barriers.
// Score phase: 4 edges/wave in parallel, 16 lanes/edge (8 ch/lane).
// Optional fused LayerNorm+ReLU epilogue (H=1 layers only).
// ---------------------------------------------------------------------------
template<int H, bool MEANH, bool LNRELU>
__global__ __launch_bounds__(256) void attn_kernel(
    const float* __restrict__ q, const float* __restrict__ k,
    const float* __restrict__ v, const float* __restrict__ skip,
    const int* __restrict__ deg, const int* __restrict__ cols,
    const float* __restrict__ evals, const float* __restrict__ We,
    float* __restrict__ out)
{
    const int HD = H * DD;
    int wid  = threadIdx.x >> 6;
    int lane = threadIdx.x & 63;
    int row  = blockIdx.x * 4 + wid;
    int sub  = lane >> 4;          // edge slot within a 4-edge group
    int s    = lane & 15;          // 8-channel slice within an edge

    __shared__ float sc_s[4][H][CAP];
    __shared__ int   jc_s[4][CAP];
    __shared__ float ev_s[4][CAP];
    float (*sc)[CAP] = sc_s[wid];
    int*   jc = jc_s[wid];
    float* ev = ev_s[wid];

    int dg = min(deg[row], CAP);

    for (int m = lane; m < dg; m += 64) {
        jc[m] = cols[row * CAP + m];
        ev[m] = evals[row * CAP + m];
    }

    // q fragment: channels s*8..s*8+7 per head (replicated across subgroups),
    // plus qe[h] = q . We[h] via 16-lane butterfly.
    float qh[H][8];
    float qe[H];
#pragma unroll
    for (int h = 0; h < H; h++) {
        const float* qp = &q[(size_t)row * HD + h * DD + s * 8];
        const float* wp = &We[h * DD + s * 8];
        float pe = 0.f;
#pragma unroll
        for (int t = 0; t < 8; t++) { qh[h][t] = qp[t]; pe += qp[t] * wp[t]; }
#pragma unroll
        for (int off = 8; off; off >>= 1) pe += __shfl_xor(pe, off);
        qe[h] = pe;
    }

    // ---- scores: 4 edges per iteration ----
    for (int m0 = 0; m0 < dg; m0 += 4) {
        int  e  = m0 + sub;
        bool ok = e < dg;
        int  j  = jc[ok ? e : m0];
        float ee = ok ? ev[e] : 0.f;
#pragma unroll
        for (int h = 0; h < H; h++) {
            const float* kr = &k[(size_t)j * HD + h * DD + s * 8];
            float p = 0.f;
#pragma unroll
            for (int t = 0; t < 8; t++) p += qh[h][t] * kr[t];
#pragma unroll
            for (int off = 8; off; off >>= 1) p += __shfl_xor(p, off);
            if (ok && s == 0) sc[h][e] = (p + qe[h] * ee) * INV_SQRT_D;
        }
    }

    // ---- softmax + ew (full-wave butterfly; 2 scores/lane) ----
    float invZ[H], ews[H];
#pragma unroll
    for (int h = 0; h < H; h++) {
        float s0 = (lane < dg)      ? sc[h][lane]      : -INFINITY;
        float s1 = (lane + 64 < dg) ? sc[h][lane + 64] : -INFINITY;
        float mx = fmaxf(s0, s1);
#pragma unroll
        for (int off = 32; off; off >>= 1) mx = fmaxf(mx, __shfl_xor(mx, off));
        float e0 = (lane < dg)      ? __expf(s0 - mx) : 0.f;
        float e1 = (lane + 64 < dg) ? __expf(s1 - mx) : 0.f;
        if (lane < dg)      sc[h][lane]      = e0;
        if (lane + 64 < dg) sc[h][lane + 64] = e1;
        float z  = e0 + e1;
        float ew = e0 * ((lane < dg) ? ev[lane] : 0.f)
                 + e1 * ((lane + 64 < dg) ? ev[lane + 64] : 0.f);
#pragma unroll
        for (int off = 32; off; off >>= 1) { z += __shfl_xor(z, off); ew += __shfl_xor(ew, off); }
        invZ[h] = (z > 0.f) ? 1.f / z : 0.f;
        ews[h]  = ew;
    }

    // ---- aggregation: float2 per lane per head ----
    int c0 = lane * 2;
    float acc[H][2];
#pragma unroll
    for (int h = 0; h < H; h++) { acc[h][0] = 0.f; acc[h][1] = 0.f; }
#pragma unroll 4
    for (int m = 0; m < dg; m++) {
        int j = jc[m];
#pragma unroll
        for (int h = 0; h < H; h++) {
            float  al = sc[h][m];
            float2 vv = *(const float2*)&v[(size_t)j * HD + h * DD + c0];
            acc[h][0] += al * vv.x;
            acc[h][1] += al * vv.y;
        }
    }

    // ---- epilogue ----
    float rh[H][2];
#pragma unroll
    for (int h = 0; h < H; h++) {
        rh[h][0] = (acc[h][0] + ews[h] * We[h * DD + c0])     * invZ[h];
        rh[h][1] = (acc[h][1] + ews[h] * We[h * DD + c0 + 1]) * invZ[h];
    }
    float r0, r1;
    if constexpr (MEANH) {
        r0 = 0.5f * (rh[0][0] + rh[H - 1][0]);
        r1 = 0.5f * (rh[0][1] + rh[H - 1][1]);
    } else {
        r0 = rh[0][0]; r1 = rh[0][1];
    }
    float2 sk = *(const float2*)&skip[(size_t)row * DD + c0];
    r0 += sk.x; r1 += sk.y;

    if constexpr (LNRELU) {
        float sum = r0 + r1, sq = r0 * r0 + r1 * r1;
#pragma unroll
        for (int off = 32; off; off >>= 1) { sum += __shfl_xor(sum, off); sq += __shfl_xor(sq, off); }
        float mu  = sum * (1.f / DD);
        float var = sq * (1.f / DD) - mu * mu;
        float rs  = rsqrtf(var + 1e-5f);
        r0 = fmaxf((r0 - mu) * rs, 0.f);
        r1 = fmaxf((r1 - mu) * rs, 0.f);
    }
    float2 res; res.x = r0; res.y = r1;
    *(float2*)&out[(size_t)row * DD + c0] = res;
}

// ---------------------------------------------------------------------------
extern "C" void kernel_launch(void* const* d_in, const int* in_sizes, int n_in,
                              void* d_out, int out_size, void* d_ws, size_t ws_size,
                              hipStream_t stream)
{
    const float* node = (const float*)d_in[0];
    const float* edge = (const float*)d_in[1];
    const float* A    = (const float*)d_in[2];
    const float* Wq[3] = {(const float*)d_in[3],  (const float*)d_in[8],  (const float*)d_in[13]};
    const float* Wk[3] = {(const float*)d_in[4],  (const float*)d_in[9],  (const float*)d_in[14]};
    const float* Wv[3] = {(const float*)d_in[5],  (const float*)d_in[10], (const float*)d_in[15]};
    const float* We[3] = {(const float*)d_in[6],  (const float*)d_in[11], (const float*)d_in[16]};
    const float* Ws[3] = {(const float*)d_in[7],  (const float*)d_in[12], (const float*)d_in[17]};

    // workspace carve
    char* p = (char*)d_ws;
    float* emb_a = (float*)p; p += (size_t)BN * DD * 4;
    float* emb_b = (float*)p; p += (size_t)BN * DD * 4;
    float* qbuf  = (float*)p; p += (size_t)BN * 256 * 4;
    float* kbuf  = (float*)p; p += (size_t)BN * 256 * 4;
    float* vbuf  = (float*)p; p += (size_t)BN * 256 * 4;
    float* sbuf  = (float*)p; p += (size_t)BN * DD * 4;
    int*   degb  = (int*)p;   p += (size_t)BN * 4;
    int*   colb  = (int*)p;   p += (size_t)BN * CAP * 4;
    float* evb   = (float*)p; p += (size_t)BN * CAP * 4;

    hipMemsetAsync(degb, 0, (size_t)BN * 4, stream);
    build_csr<<<(BB * NN * NN) / 256, 256, 0, stream>>>(A, edge, degb, colb, evb);
    cast_node<<<BN / 256, 256, 0, stream>>>(node, emb_a);

    float* x = emb_a;
    float* y = emb_b;

    // layer schedule: (layer idx, fused LN+ReLU)
    const int  appL [7] = {0, 1, 2, 1, 2, 1, 2};

    for (int a = 0; a < 7; a++) {
        int l = appL[a];
        int H = (l == 2) ? 2 : 1;
        int ncols = 3 * H * DD + DD;
        dim3 pgrid(BN / 16, ncols / 128);
        if (l == 0)
            proj_kernel<1><<<pgrid, 128, 0, stream>>>(x, Wq[l], Wk[l], Wv[l], Ws[l],
                                                      qbuf, kbuf, vbuf, sbuf, H);
        else
            proj_kernel<DD><<<pgrid, 128, 0, stream>>>(x, Wq[l], Wk[l], Wv[l], Ws[l],
                                                       qbuf, kbuf, vbuf, sbuf, H);
        float* dst = (a == 6) ? (float*)d_out : y;
        if (l == 2)
            attn_kernel<2, true, false><<<BN / 4, 256, 0, stream>>>(
                qbuf, kbuf, vbuf, sbuf, degb, colb, evb, We[l], dst);
        else
            attn_kernel<1, false, true><<<BN / 4, 256, 0, stream>>>(
                qbuf, kbuf, vbuf, sbuf, degb, colb, evb, We[l], dst);
        float* t = x; x = dst; y = t;
    }
}

// Round 4
// 528.945 us; speedup vs baseline: 1.6051x; 1.0911x over previous
//
#include <hip/hip_runtime.h>
#include <hip/hip_bf16.h>

#define BB 2
#define NN 2048
#define DD 128
#define BN (BB*NN)
#define CAP 128
#define TD 16
#define INV_SQRT_D 0.08838834764831845f

// ---------------------------------------------------------------------------
// LDS-tiled CSR build of e_t[b,dst,src] = edge[b,src,dst]*A[b,src,dst].
// One block per (b, 16-dst tile). Coalesced float4 reads (one 64B line per
// src row per array per block), LDS-atomic compaction, coalesced writeout.
// cols[] stores GLOBAL src row (b*NN + src).
// ---------------------------------------------------------------------------
__global__ __launch_bounds__(256) void build_csr(
    const float* __restrict__ A,
    const float* __restrict__ edge,
    int* __restrict__ deg, int* __restrict__ cols, float* __restrict__ evals)
{
    __shared__ int   cnt[TD];
    __shared__ int   csh[TD][CAP];
    __shared__ float esh[TD][CAP];

    int bid  = blockIdx.x;
    int b    = bid / (NN / TD);
    int dst0 = (bid % (NN / TD)) * TD;
    int tid  = threadIdx.x;

    if (tid < TD) cnt[tid] = 0;
    __syncthreads();

    int srcOff = tid >> 2;          // 0..63
    int dOff   = (tid & 3) * 4;     // 0,4,8,12
    const size_t base = (size_t)b * NN * NN + dst0 + dOff;

#pragma unroll 2
    for (int s0 = 0; s0 < NN; s0 += 64) {
        int src = s0 + srcOff;
        float4 a4 = *(const float4*)&A[base + (size_t)src * NN];
        float4 e4 = *(const float4*)&edge[base + (size_t)src * NN];
        int gsrc = b * NN + src;
        float av[4] = {a4.x, a4.y, a4.z, a4.w};
        float ev[4] = {e4.x, e4.y, e4.z, e4.w};
#pragma unroll
        for (int u = 0; u < 4; u++) {
            if (av[u] != 0.f) {
                int d = dOff + u;
                int slot = atomicAdd(&cnt[d], 1);
                if (slot < CAP) { csh[d][slot] = gsrc; esh[d][slot] = ev[u] * av[u]; }
            }
        }
    }
    __syncthreads();

    if (tid < TD) deg[b * NN + dst0 + tid] = min(cnt[tid], CAP);
    for (int idx = tid; idx < TD * CAP; idx += 256) {
        int d = idx / CAP, i = idx % CAP;
        if (i < min(cnt[d], CAP)) {
            size_t row = (size_t)(b * NN + dst0 + d);
            cols [row * CAP + i] = csh[d][i];
            evals[row * CAP + i] = esh[d][i];
        }
    }
}

__global__ __launch_bounds__(256) void cast_node(
    const float* __restrict__ node, float* __restrict__ x0)
{
    int i = blockIdx.x * blockDim.x + threadIdx.x;   // BN
    x0[i] = node[i];
}

// ---------------------------------------------------------------------------
// Fused projection: out cols = [ q(H*D) | k(H*D) | v(H*D) | skip(D) ]
// grid: (BN/16, ncols/128), block 128.  Each block: 16 rows x 128 cols.
// ---------------------------------------------------------------------------
template<int FIN>
__global__ __launch_bounds__(128) void proj_kernel(
    const float* __restrict__ x,
    const float* __restrict__ Wq,
    const float* __restrict__ Wk,
    const float* __restrict__ Wv,
    const float* __restrict__ Ws,
    float* __restrict__ q, float* __restrict__ k,
    float* __restrict__ v, float* __restrict__ skip,
    int H)
{
    const int HD = H * DD;
    __shared__ float xs[16][FIN];
    int row0 = blockIdx.x * 16;
    int col  = blockIdx.y * 128 + threadIdx.x;

    if constexpr (FIN % 4 == 0) {
        const float4* xp  = (const float4*)&x[(size_t)row0 * FIN];
        float4*       xsp = (float4*)&xs[0][0];
        for (int i = threadIdx.x; i < 16 * FIN / 4; i += 128) xsp[i] = xp[i];
    } else {
        for (int idx = threadIdx.x; idx < 16 * FIN; idx += 128)
            xs[idx / FIN][idx % FIN] = x[(size_t)(row0 + idx / FIN) * FIN + idx % FIN];
    }
    __syncthreads();

    const float* W; float* out; int lcol; int ldw; int odim;
    if      (col < HD)     { W = Wq; out = q;    lcol = col;          ldw = HD; odim = HD; }
    else if (col < 2*HD)   { W = Wk; out = k;    lcol = col - HD;     ldw = HD; odim = HD; }
    else if (col < 3*HD)   { W = Wv; out = v;    lcol = col - 2*HD;   ldw = HD; odim = HD; }
    else                   { W = Ws; out = skip; lcol = col - 3*HD;   ldw = DD; odim = DD; }

    float acc[16];
#pragma unroll
    for (int r = 0; r < 16; r++) acc[r] = 0.f;
    for (int f = 0; f < FIN; f++) {
        float wf = W[(size_t)f * ldw + lcol];
#pragma unroll
        for (int r = 0; r < 16; r++) acc[r] += xs[r][f] * wf;
    }
#pragma unroll
    for (int r = 0; r < 16; r++) out[(size_t)(row0 + r) * odim + lcol] = acc[r];
}

// ---------------------------------------------------------------------------
// Single-pass online-softmax sparse transformer-conv attention.
// One wave per dst row, 4 rows/block. Per 4-edge group: issue k (2xfloat4)
// and 4xH v (float2/lane) loads up front, 16-lane butterfly scores,
// flash-style rescale, immediate v accumulation. No score LDS round-trip.
// Optional fused LayerNorm+ReLU epilogue (H=1 layers only).
// ---------------------------------------------------------------------------
template<int H, bool MEANH, bool LNRELU>
__global__ __launch_bounds__(256) void attn_kernel(
    const float* __restrict__ q, const float* __restrict__ k,
    const float* __restrict__ v, const float* __restrict__ skip,
    const int* __restrict__ deg, const int* __restrict__ cols,
    const float* __restrict__ evals, const float* __restrict__ We,
    float* __restrict__ out)
{
    const int HD = H * DD;
    int wid  = threadIdx.x >> 6;
    int lane = threadIdx.x & 63;
    int row  = blockIdx.x * 4 + wid;
    int sub  = lane >> 4;          // edge slot within a 4-edge group
    int s    = lane & 15;          // 8-channel slice within an edge
    int c0   = lane * 2;

    __shared__ int   jc_s[4][CAP];
    __shared__ float ev_s[4][CAP];
    int*   jc = jc_s[wid];
    float* ev = ev_s[wid];

    int dg = min(deg[row], CAP);
    for (int m = lane; m < dg; m += 64) {
        jc[m] = cols[(size_t)row * CAP + m];
        ev[m] = evals[(size_t)row * CAP + m];
    }
    __syncthreads();

    // q fragment (channels s*8..s*8+7 per head) + qe[h] = q . We[h]
    float qh[H][8];
    float qe[H];
#pragma unroll
    for (int h = 0; h < H; h++) {
        const float* qp = &q[(size_t)row * HD + h * DD + s * 8];
        const float* wp = &We[h * DD + s * 8];
        float pe = 0.f;
#pragma unroll
        for (int t = 0; t < 8; t++) { qh[h][t] = qp[t]; pe += qp[t] * wp[t]; }
#pragma unroll
        for (int off = 1; off < 16; off <<= 1) pe += __shfl_xor(pe, off);
        qe[h] = pe;
    }

    float m_run[H], l_run[H], ew_run[H], acc[H][2];
#pragma unroll
    for (int h = 0; h < H; h++) {
        m_run[h] = -INFINITY; l_run[h] = 0.f; ew_run[h] = 0.f;
        acc[h][0] = 0.f; acc[h][1] = 0.f;
    }

    for (int m0 = 0; m0 < dg; m0 += 4) {
        // this subgroup's edge (for the score dot product)
        int   e  = m0 + sub;
        bool  ok = e < dg;
        int   ec = ok ? e : m0;
        int   j  = jc[ec];
        float ee = ev[ec];

        // all 4 edges' (j, e) + v prefetch (independent loads)
        int jb[4]; float eb[4];
#pragma unroll
        for (int es = 0; es < 4; es++) {
            int mc = (m0 + es < dg) ? m0 + es : m0;
            jb[es] = jc[mc]; eb[es] = ev[mc];
        }
        float2 vv[H][4];
#pragma unroll
        for (int h = 0; h < H; h++)
#pragma unroll
            for (int es = 0; es < 4; es++)
                vv[h][es] = *(const float2*)&v[(size_t)jb[es] * HD + h * DD + c0];

        // scores (16 lanes per edge, 8 ch/lane)
        float sc4[H];
#pragma unroll
        for (int h = 0; h < H; h++) {
            const float* kr = &k[(size_t)j * HD + h * DD + s * 8];
            float4 k0 = *(const float4*)kr;
            float4 k1 = *(const float4*)(kr + 4);
            float p = qh[h][0]*k0.x + qh[h][1]*k0.y + qh[h][2]*k0.z + qh[h][3]*k0.w
                    + qh[h][4]*k1.x + qh[h][5]*k1.y + qh[h][6]*k1.z + qh[h][7]*k1.w;
#pragma unroll
            for (int off = 1; off < 16; off <<= 1) p += __shfl_xor(p, off);
            sc4[h] = ok ? (p + qe[h] * ee) * INV_SQRT_D : -INFINITY;
        }

        // online-softmax update + accumulate
#pragma unroll
        for (int h = 0; h < H; h++) {
            float g = sc4[h];
            g = fmaxf(g, __shfl_xor(g, 16));
            g = fmaxf(g, __shfl_xor(g, 32));        // max over the 4 edges
            float newm  = fmaxf(m_run[h], g);       // finite: edge m0 is valid
            float scale = __expf(m_run[h] - newm);  // first iter: exp(-inf)=0
            m_run[h] = newm;
            acc[h][0] *= scale; acc[h][1] *= scale;
            l_run[h] *= scale;  ew_run[h] *= scale;
#pragma unroll
            for (int es = 0; es < 4; es++) {
                float al = __expf(__shfl(sc4[h], es * 16) - newm); // 0 for invalid
                acc[h][0] += al * vv[h][es].x;
                acc[h][1] += al * vv[h][es].y;
                l_run[h]  += al;
                ew_run[h] += al * eb[es];
            }
        }
    }

    // ---- epilogue ----
    float rh[H][2];
#pragma unroll
    for (int h = 0; h < H; h++) {
        float invZ = (l_run[h] > 0.f) ? 1.f / l_run[h] : 0.f;
        rh[h][0] = (acc[h][0] + ew_run[h] * We[h * DD + c0])     * invZ;
        rh[h][1] = (acc[h][1] + ew_run[h] * We[h * DD + c0 + 1]) * invZ;
    }
    float r0, r1;
    if constexpr (MEANH) {
        r0 = 0.5f * (rh[0][0] + rh[H - 1][0]);
        r1 = 0.5f * (rh[0][1] + rh[H - 1][1]);
    } else {
        r0 = rh[0][0]; r1 = rh[0][1];
    }
    float2 sk = *(const float2*)&skip[(size_t)row * DD + c0];
    r0 += sk.x; r1 += sk.y;

    if constexpr (LNRELU) {
        float sum = r0 + r1, sq = r0 * r0 + r1 * r1;
#pragma unroll
        for (int off = 32; off; off >>= 1) { sum += __shfl_xor(sum, off); sq += __shfl_xor(sq, off); }
        float mu  = sum * (1.f / DD);
        float var = sq * (1.f / DD) - mu * mu;
        float rs  = rsqrtf(var + 1e-5f);
        r0 = fmaxf((r0 - mu) * rs, 0.f);
        r1 = fmaxf((r1 - mu) * rs, 0.f);
    }
    float2 res; res.x = r0; res.y = r1;
    *(float2*)&out[(size_t)row * DD + c0] = res;
}

// ---------------------------------------------------------------------------
extern "C" void kernel_launch(void* const* d_in, const int* in_sizes, int n_in,
                              void* d_out, int out_size, void* d_ws, size_t ws_size,
                              hipStream_t stream)
{
    const float* node = (const float*)d_in[0];
    const float* edge = (const float*)d_in[1];
    const float* A    = (const float*)d_in[2];
    const float* Wq[3] = {(const float*)d_in[3],  (const float*)d_in[8],  (const float*)d_in[13]};
    const float* Wk[3] = {(const float*)d_in[4],  (const float*)d_in[9],  (const float*)d_in[14]};
    const float* Wv[3] = {(const float*)d_in[5],  (const float*)d_in[10], (const float*)d_in[15]};
    const float* We[3] = {(const float*)d_in[6],  (const float*)d_in[11], (const float*)d_in[16]};
    const float* Ws[3] = {(const float*)d_in[7],  (const float*)d_in[12], (const float*)d_in[17]};

    // workspace carve
    char* p = (char*)d_ws;
    float* emb_a = (float*)p; p += (size_t)BN * DD * 4;
    float* emb_b = (float*)p; p += (size_t)BN * DD * 4;
    float* qbuf  = (float*)p; p += (size_t)BN * 256 * 4;
    float* kbuf  = (float*)p; p += (size_t)BN * 256 * 4;
    float* vbuf  = (float*)p; p += (size_t)BN * 256 * 4;
    float* sbuf  = (float*)p; p += (size_t)BN * DD * 4;
    int*   degb  = (int*)p;   p += (size_t)BN * 4;
    int*   colb  = (int*)p;   p += (size_t)BN * CAP * 4;
    float* evb   = (float*)p; p += (size_t)BN * CAP * 4;

    build_csr<<<BB * (NN / TD), 256, 0, stream>>>(A, edge, degb, colb, evb);
    cast_node<<<BN / 256, 256, 0, stream>>>(node, emb_a);

    float* x = emb_a;
    float* y = emb_b;

    const int appL[7] = {0, 1, 2, 1, 2, 1, 2};

    for (int a = 0; a < 7; a++) {
        int l = appL[a];
        int H = (l == 2) ? 2 : 1;
        int ncols = 3 * H * DD + DD;
        dim3 pgrid(BN / 16, ncols / 128);
        if (l == 0)
            proj_kernel<1><<<pgrid, 128, 0, stream>>>(x, Wq[l], Wk[l], Wv[l], Ws[l],
                                                      qbuf, kbuf, vbuf, sbuf, H);
        else
            proj_kernel<DD><<<pgrid, 128, 0, stream>>>(x, Wq[l], Wk[l], Wv[l], Ws[l],
                                                       qbuf, kbuf, vbuf, sbuf, H);
        float* dst = (a == 6) ? (float*)d_out : y;
        if (l == 2)
            attn_kernel<2, true, false><<<BN / 4, 256, 0, stream>>>(
                qbuf, kbuf, vbuf, sbuf, degb, colb, evb, We[l], dst);
        else
            attn_kernel<1, false, true><<<BN / 4, 256, 0, stream>>>(
                qbuf, kbuf, vbuf, sbuf, degb, colb, evb, We[l], dst);
        float* t = x; x = dst; y = t;
    }
}

// Round 5
// 390.428 us; speedup vs baseline: 2.1745x; 1.3548x over previous
//
#include <hip/hip_runtime.h>
#include <hip/hip_bf16.h>

#define BB 2
#define NN 2048
#define DD 128
#define BN (BB*NN)
#define CAP 128
#define TD 16
#define INV_SQRT_D 0.08838834764831845f

typedef __attribute__((ext_vector_type(8))) short short8;
typedef __attribute__((ext_vector_type(4))) float f32x4;

// ---------------------------------------------------------------------------
// LDS-tiled CSR build of e_t[b,dst,src] = edge[b,src,dst]*A[b,src,dst].
// cols[] stores GLOBAL src row (b*NN + src).
// ---------------------------------------------------------------------------
__global__ __launch_bounds__(256) void build_csr(
    const float* __restrict__ A,
    const float* __restrict__ edge,
    int* __restrict__ deg, int* __restrict__ cols, float* __restrict__ evals)
{
    __shared__ int   cnt[TD];
    __shared__ int   csh[TD][CAP];
    __shared__ float esh[TD][CAP];

    int bid  = blockIdx.x;
    int b    = bid / (NN / TD);
    int dst0 = (bid % (NN / TD)) * TD;
    int tid  = threadIdx.x;

    if (tid < TD) cnt[tid] = 0;
    __syncthreads();

    int srcOff = tid >> 2;
    int dOff   = (tid & 3) * 4;
    const size_t base = (size_t)b * NN * NN + dst0 + dOff;

#pragma unroll 2
    for (int s0 = 0; s0 < NN; s0 += 64) {
        int src = s0 + srcOff;
        float4 a4 = *(const float4*)&A[base + (size_t)src * NN];
        float4 e4 = *(const float4*)&edge[base + (size_t)src * NN];
        int gsrc = b * NN + src;
        float av[4] = {a4.x, a4.y, a4.z, a4.w};
        float ev[4] = {e4.x, e4.y, e4.z, e4.w};
#pragma unroll
        for (int u = 0; u < 4; u++) {
            if (av[u] != 0.f) {
                int d = dOff + u;
                int slot = atomicAdd(&cnt[d], 1);
                if (slot < CAP) { csh[d][slot] = gsrc; esh[d][slot] = ev[u] * av[u]; }
            }
        }
    }
    __syncthreads();

    if (tid < TD) deg[b * NN + dst0 + tid] = min(cnt[tid], CAP);
    for (int idx = tid; idx < TD * CAP; idx += 256) {
        int d = idx / CAP, i = idx % CAP;
        if (i < min(cnt[d], CAP)) {
            size_t row = (size_t)(b * NN + dst0 + d);
            cols [row * CAP + i] = csh[d][i];
            evals[row * CAP + i] = esh[d][i];
        }
    }
}

// ---------------------------------------------------------------------------
// Weight prep: Wt[n][k] = W*[k][n] as bf16, cols concat [q | k | v | skip].
// grid = ncols blocks, 128 threads (k).
// ---------------------------------------------------------------------------
__global__ __launch_bounds__(128) void prep_weights(
    const float* __restrict__ Wq, const float* __restrict__ Wk,
    const float* __restrict__ Wv, const float* __restrict__ Ws,
    __hip_bfloat16* __restrict__ Wt, int HD)
{
    int n = blockIdx.x;
    int t = threadIdx.x;
    const float* src; int ld; int col;
    if      (n < HD)     { src = Wq; col = n;          ld = HD; }
    else if (n < 2*HD)   { src = Wk; col = n - HD;     ld = HD; }
    else if (n < 3*HD)   { src = Wv; col = n - 2*HD;   ld = HD; }
    else                 { src = Ws; col = n - 3*HD;   ld = DD; }
    Wt[(size_t)n * DD + t] = __float2bfloat16(src[(size_t)t * ld + col]);
}

// ---------------------------------------------------------------------------
// Layer-0 projection (FIN=1, rank-1): block = 16 rows x 128 cols.
// ---------------------------------------------------------------------------
__global__ __launch_bounds__(128) void proj_l0(
    const float* __restrict__ x,
    const float* __restrict__ Wq, const float* __restrict__ Wk,
    const float* __restrict__ Wv, const float* __restrict__ Ws,
    float* __restrict__ q, float* __restrict__ k,
    float* __restrict__ v, float* __restrict__ skip)
{
    __shared__ float xs[16];
    int row0 = blockIdx.x * 16;
    int col  = blockIdx.y * 128 + threadIdx.x;
    if (threadIdx.x < 16) xs[threadIdx.x] = x[row0 + threadIdx.x];
    __syncthreads();

    const float* W; float* out; int lcol;
    if      (col < DD)     { W = Wq; out = q;    lcol = col;          }
    else if (col < 2*DD)   { W = Wk; out = k;    lcol = col - DD;     }
    else if (col < 3*DD)   { W = Wv; out = v;    lcol = col - 2*DD;   }
    else                   { W = Ws; out = skip; lcol = col - 3*DD;   }
    float wf = W[lcol];
#pragma unroll
    for (int r = 0; r < 16; r++) out[(size_t)(row0 + r) * DD + lcol] = xs[r] * wf;
}

// ---------------------------------------------------------------------------
// MFMA bf16 projection: x_bf16 (BN x 128) @ Wt^T -> [q|k|v|skip] fp32.
// Wave = 16x64 output tile (4 n-tiles), K=128 in 4 steps, no LDS.
// A frag: lane m=lane&15, k=quad*8+j (contig 16B). B frag: Wt[n][k] same.
// C/D: col=lane&15, row=quad*4+reg  [m89-verified layout].
// grid (BN/64, NCOLS/64), block 256 (4 waves = 4 m-tiles).
// ---------------------------------------------------------------------------
template<int NCOLS, int HD>
__global__ __launch_bounds__(256) void proj_mfma(
    const __hip_bfloat16* __restrict__ xb,
    const __hip_bfloat16* __restrict__ Wt,
    float* __restrict__ q, float* __restrict__ k,
    float* __restrict__ v, float* __restrict__ skip)
{
    int wid  = threadIdx.x >> 6, lane = threadIdx.x & 63;
    int row0 = blockIdx.x * 64 + wid * 16;
    int n0   = blockIdx.y * 64;
    int m    = lane & 15, quad = lane >> 4;

    float* out; int lc0, odim;
    if      (n0 < HD)     { out = q;    lc0 = n0;          odim = HD; }
    else if (n0 < 2*HD)   { out = k;    lc0 = n0 - HD;     odim = HD; }
    else if (n0 < 3*HD)   { out = v;    lc0 = n0 - 2*HD;   odim = HD; }
    else                  { out = skip; lc0 = n0 - 3*HD;   odim = DD; }

    f32x4 acc[4] = {f32x4{0,0,0,0}, f32x4{0,0,0,0}, f32x4{0,0,0,0}, f32x4{0,0,0,0}};
    const short8* ap = (const short8*)&xb[(size_t)(row0 + m) * DD + quad * 8];
#pragma unroll
    for (int ks = 0; ks < 4; ks++) {
        short8 a = ap[ks * 4];                       // +32 elems per k-step
#pragma unroll
        for (int t = 0; t < 4; t++) {
            const short8* bp = (const short8*)&Wt[(size_t)(n0 + t * 16 + m) * DD + ks * 32 + quad * 8];
            acc[t] = __builtin_amdgcn_mfma_f32_16x16x32_bf16(a, *bp, acc[t], 0, 0, 0);
        }
    }
#pragma unroll
    for (int t = 0; t < 4; t++)
#pragma unroll
        for (int r = 0; r < 4; r++)
            out[(size_t)(row0 + quad * 4 + r) * odim + lc0 + t * 16 + m] = acc[t][r];
}

// ---------------------------------------------------------------------------
// Single-pass sparse attention, NO online max (scores bounded; clamp 60).
// One wave per dst, 4/block. 4 edges/group, 16 lanes/edge.
// Optional fused LN+ReLU; optional bf16 output (intermediate layers).
// ---------------------------------------------------------------------------
template<int H, bool MEANH, bool LNRELU, bool OUTBF>
__global__ __launch_bounds__(256) void attn_kernel(
    const float* __restrict__ q, const float* __restrict__ k,
    const float* __restrict__ v, const float* __restrict__ skip,
    const int* __restrict__ deg, const int* __restrict__ cols,
    const float* __restrict__ evals, const float* __restrict__ We,
    void* __restrict__ outv)
{
    const int HD = H * DD;
    int wid  = threadIdx.x >> 6;
    int lane = threadIdx.x & 63;
    int row  = blockIdx.x * 4 + wid;
    int sub  = lane >> 4;
    int s    = lane & 15;
    int c0   = lane * 2;

    __shared__ int   jc_s[4][CAP];
    __shared__ float ev_s[4][CAP];
    int*   jc = jc_s[wid];
    float* ev = ev_s[wid];

    int dg = min(deg[row], CAP);
    for (int m = lane; m < dg; m += 64) {
        jc[m] = cols[(size_t)row * CAP + m];
        ev[m] = evals[(size_t)row * CAP + m];
    }
    // wave-private LDS: no barrier needed (compiler inserts lgkmcnt waits)

    float qh[H][8];
    float qeI[H];
#pragma unroll
    for (int h = 0; h < H; h++) {
        const float* qp = &q[(size_t)row * HD + h * DD + s * 8];
        const float* wp = &We[h * DD + s * 8];
        float pe = 0.f;
#pragma unroll
        for (int t = 0; t < 8; t++) { qh[h][t] = qp[t]; pe += qp[t] * wp[t]; }
#pragma unroll
        for (int off = 1; off < 16; off <<= 1) pe += __shfl_xor(pe, off);
        qeI[h] = pe * INV_SQRT_D;
    }

    float l_acc[H], ew_acc[H], acc[H][2];
#pragma unroll
    for (int h = 0; h < H; h++) { l_acc[h] = 0.f; ew_acc[h] = 0.f; acc[h][0] = 0.f; acc[h][1] = 0.f; }

    for (int m0 = 0; m0 < dg; m0 += 4) {
        int   e  = m0 + sub;
        bool  ok = e < dg;
        int   ec = ok ? e : m0;
        int   j  = jc[ec];
        float ee = ev[ec];

        int jb[4];
#pragma unroll
        for (int es = 0; es < 4; es++) jb[es] = jc[(m0 + es < dg) ? m0 + es : m0];
        float2 vv[H][4];
#pragma unroll
        for (int h = 0; h < H; h++)
#pragma unroll
            for (int es = 0; es < 4; es++)
                vv[h][es] = *(const float2*)&v[(size_t)jb[es] * HD + h * DD + c0];

#pragma unroll
        for (int h = 0; h < H; h++) {
            const float* kr = &k[(size_t)j * HD + h * DD + s * 8];
            float4 k0 = *(const float4*)kr;
            float4 k1 = *(const float4*)(kr + 4);
            float p = qh[h][0]*k0.x + qh[h][1]*k0.y + qh[h][2]*k0.z + qh[h][3]*k0.w
                    + qh[h][4]*k1.x + qh[h][5]*k1.y + qh[h][6]*k1.z + qh[h][7]*k1.w;
#pragma unroll
            for (int off = 1; off < 16; off <<= 1) p += __shfl_xor(p, off);
            float sc = ok ? (p * INV_SQRT_D + qeI[h] * ee) : -1e30f;
            float a4 = __expf(fminf(sc, 60.f));       // invalid -> exp(-1e30)=0
            l_acc[h]  += a4;                          // subgroup-local (x16 replicated)
            ew_acc[h] += a4 * ee;
            float al[4];
#pragma unroll
            for (int es = 0; es < 4; es++) al[es] = __shfl(a4, es * 16);
#pragma unroll
            for (int es = 0; es < 4; es++) {
                acc[h][0] += al[es] * vv[h][es].x;
                acc[h][1] += al[es] * vv[h][es].y;
            }
        }
    }

    // reduce l/ew across the 4 subgroups (values replicated within subgroup)
    float rh[H][2];
#pragma unroll
    for (int h = 0; h < H; h++) {
        float l  = l_acc[h]  + __shfl_xor(l_acc[h], 16);
        float ew = ew_acc[h] + __shfl_xor(ew_acc[h], 16);
        l  += __shfl_xor(l, 32);
        ew += __shfl_xor(ew, 32);
        float invZ = (l > 0.f) ? 1.f / l : 0.f;
        rh[h][0] = (acc[h][0] + ew * We[h * DD + c0])     * invZ;
        rh[h][1] = (acc[h][1] + ew * We[h * DD + c0 + 1]) * invZ;
    }
    float r0, r1;
    if constexpr (MEANH) {
        r0 = 0.5f * (rh[0][0] + rh[H - 1][0]);
        r1 = 0.5f * (rh[0][1] + rh[H - 1][1]);
    } else {
        r0 = rh[0][0]; r1 = rh[0][1];
    }
    float2 sk = *(const float2*)&skip[(size_t)row * DD + c0];
    r0 += sk.x; r1 += sk.y;

    if constexpr (LNRELU) {
        float sum = r0 + r1, sq = r0 * r0 + r1 * r1;
#pragma unroll
        for (int off = 32; off; off >>= 1) { sum += __shfl_xor(sum, off); sq += __shfl_xor(sq, off); }
        float mu  = sum * (1.f / DD);
        float var = sq * (1.f / DD) - mu * mu;
        float rs  = rsqrtf(var + 1e-5f);
        r0 = fmaxf((r0 - mu) * rs, 0.f);
        r1 = fmaxf((r1 - mu) * rs, 0.f);
    }

    if constexpr (OUTBF) {
        __hip_bfloat16* ob = (__hip_bfloat16*)outv;
        __hip_bfloat162 o;
        o.x = __float2bfloat16(r0);
        o.y = __float2bfloat16(r1);
        *(__hip_bfloat162*)&ob[(size_t)row * DD + c0] = o;
    } else {
        float2 res; res.x = r0; res.y = r1;
        *(float2*)&((float*)outv)[(size_t)row * DD + c0] = res;
    }
}

// ---------------------------------------------------------------------------
extern "C" void kernel_launch(void* const* d_in, const int* in_sizes, int n_in,
                              void* d_out, int out_size, void* d_ws, size_t ws_size,
                              hipStream_t stream)
{
    const float* node = (const float*)d_in[0];
    const float* edge = (const float*)d_in[1];
    const float* A    = (const float*)d_in[2];
    const float* Wq[3] = {(const float*)d_in[3],  (const float*)d_in[8],  (const float*)d_in[13]};
    const float* Wk[3] = {(const float*)d_in[4],  (const float*)d_in[9],  (const float*)d_in[14]};
    const float* Wv[3] = {(const float*)d_in[5],  (const float*)d_in[10], (const float*)d_in[15]};
    const float* We[3] = {(const float*)d_in[6],  (const float*)d_in[11], (const float*)d_in[16]};
    const float* Ws[3] = {(const float*)d_in[7],  (const float*)d_in[12], (const float*)d_in[17]};

    // workspace carve
    char* p = (char*)d_ws;
    float*          qbuf = (float*)p;          p += (size_t)BN * 256 * 4;
    float*          kbuf = (float*)p;          p += (size_t)BN * 256 * 4;
    float*          vbuf = (float*)p;          p += (size_t)BN * 256 * 4;
    float*          sbuf = (float*)p;          p += (size_t)BN * DD * 4;
    __hip_bfloat16* xb   = (__hip_bfloat16*)p; p += (size_t)BN * DD * 2;
    __hip_bfloat16* Wt1  = (__hip_bfloat16*)p; p += (size_t)512 * DD * 2;
    __hip_bfloat16* Wt2  = (__hip_bfloat16*)p; p += (size_t)896 * DD * 2;
    int*            degb = (int*)p;            p += (size_t)BN * 4;
    int*            colb = (int*)p;            p += (size_t)BN * CAP * 4;
    float*          evb  = (float*)p;          p += (size_t)BN * CAP * 4;

    build_csr<<<BB * (NN / TD), 256, 0, stream>>>(A, edge, degb, colb, evb);
    prep_weights<<<512, 128, 0, stream>>>(Wq[1], Wk[1], Wv[1], Ws[1], Wt1, DD);
    prep_weights<<<896, 128, 0, stream>>>(Wq[2], Wk[2], Wv[2], Ws[2], Wt2, 2 * DD);

    const int appL[7] = {0, 1, 2, 1, 2, 1, 2};

    for (int a = 0; a < 7; a++) {
        int l = appL[a];
        if (l == 0) {
            proj_l0<<<dim3(BN / 16, 4), 128, 0, stream>>>(node, Wq[0], Wk[0], Wv[0], Ws[0],
                                                          qbuf, kbuf, vbuf, sbuf);
        } else if (l == 1) {
            proj_mfma<512, DD><<<dim3(BN / 64, 8), 256, 0, stream>>>(xb, Wt1, qbuf, kbuf, vbuf, sbuf);
        } else {
            proj_mfma<896, 2 * DD><<<dim3(BN / 64, 14), 256, 0, stream>>>(xb, Wt2, qbuf, kbuf, vbuf, sbuf);
        }
        if (l == 2) {
            if (a == 6)
                attn_kernel<2, true, false, false><<<BN / 4, 256, 0, stream>>>(
                    qbuf, kbuf, vbuf, sbuf, degb, colb, evb, We[l], d_out);
            else
                attn_kernel<2, true, false, true><<<BN / 4, 256, 0, stream>>>(
                    qbuf, kbuf, vbuf, sbuf, degb, colb, evb, We[l], xb);
        } else {
            attn_kernel<1, false, true, true><<<BN / 4, 256, 0, stream>>>(
                qbuf, kbuf, vbuf, sbuf, degb, colb, evb, We[l], xb);
        }
    }
}